// Round 1
// baseline (2898.561 us; speedup 1.0000x reference)
//
#include <hip/hip_runtime.h>
#include <math.h>

#define DD 512
#define EPSF 1e-8f
#define TM 24
#define KC 8

// ---------------- partial column sums (for init_c) ----------------
__global__ void k_colsum(const float* __restrict__ z, float* __restrict__ part, int N) {
    int t = threadIdx.x;          // 0..255 -> float2 column index
    int b = blockIdx.x;           // 0..255
    const float2* z2 = (const float2*)z;
    float2 acc = make_float2(0.f, 0.f);
    for (int r = b; r < N; r += gridDim.x) {
        float2 v = z2[(size_t)r * (DD / 2) + t];
        acc.x += v.x; acc.y += v.y;
    }
    part[(size_t)b * DD + 2 * t]     = acc.x;
    part[(size_t)b * DD + 2 * t + 1] = acc.y;
}

// ---------------- weighted partial column sums (for c) ----------------
__global__ void k_wcolsum(const float* __restrict__ z, const float* __restrict__ d2,
                          const float* __restrict__ d2min, const float* __restrict__ sinv,
                          float* __restrict__ part, int N) {
    int t = threadIdx.x;
    int b = blockIdx.x;
    float m  = d2min[0];
    float is = sinv[0];
    const float2* z2 = (const float2*)z;
    float2 acc = make_float2(0.f, 0.f);
    for (int r = b; r < N; r += gridDim.x) {
        float w = expf(-2.0f * (d2[r] - m)) * is;   // softmax(-d2/tau), tau=0.5
        float2 v = z2[(size_t)r * (DD / 2) + t];
        acc.x += w * v.x; acc.y += w * v.y;
    }
    part[(size_t)b * DD + 2 * t]     = acc.x;
    part[(size_t)b * DD + 2 * t + 1] = acc.y;
}

// reduce 256 partial vectors -> one [512] vector, scaled
__global__ void k_reduce_cols(const float* __restrict__ part, float* __restrict__ outv, float scale) {
    int j = blockIdx.x * blockDim.x + threadIdx.x;  // 0..511
    float s = 0.f;
    for (int p = 0; p < 256; ++p) s += part[(size_t)p * DD + j];
    outv[j] = s * scale;
}

// ---------------- d2[i] = ||z_i - init_c||^2, one wave per row ----------------
__global__ void k_d2(const float* __restrict__ z, const float* __restrict__ cbar,
                     float* __restrict__ d2, int N) {
    int lane = threadIdx.x & 63;
    int gw = (blockIdx.x * blockDim.x + threadIdx.x) >> 6;
    int nw = (gridDim.x * blockDim.x) >> 6;
    const float4* c4 = (const float4*)cbar;
    float4 ca = c4[lane];
    float4 cb = c4[lane + 64];
    for (int r = gw; r < N; r += nw) {
        const float4* zr = (const float4*)(z + (size_t)r * DD);
        float4 a  = zr[lane];
        float4 bb = zr[lane + 64];
        float d, s = 0.f;
        d = a.x  - ca.x; s += d * d;
        d = a.y  - ca.y; s += d * d;
        d = a.z  - ca.z; s += d * d;
        d = a.w  - ca.w; s += d * d;
        d = bb.x - cb.x; s += d * d;
        d = bb.y - cb.y; s += d * d;
        d = bb.z - cb.z; s += d * d;
        d = bb.w - cb.w; s += d * d;
        #pragma unroll
        for (int off = 32; off > 0; off >>= 1) s += __shfl_down(s, off, 64);
        if (lane == 0) d2[r] = s;
    }
}

// ---------------- min(d2) two-stage ----------------
__global__ void k_min_part(const float* __restrict__ d2, float* __restrict__ outp, int N) {
    __shared__ float sm[256];
    float m = 3.402823466e+38f;
    for (int i = blockIdx.x * blockDim.x + threadIdx.x; i < N; i += gridDim.x * blockDim.x)
        m = fminf(m, d2[i]);
    sm[threadIdx.x] = m;
    __syncthreads();
    for (int s = 128; s > 0; s >>= 1) {
        if (threadIdx.x < s) sm[threadIdx.x] = fminf(sm[threadIdx.x], sm[threadIdx.x + s]);
        __syncthreads();
    }
    if (threadIdx.x == 0) outp[blockIdx.x] = sm[0];
}

__global__ void k_min_final(const float* __restrict__ inp, float* __restrict__ outp) {
    __shared__ float sm[256];
    sm[threadIdx.x] = inp[threadIdx.x];
    __syncthreads();
    for (int s = 128; s > 0; s >>= 1) {
        if (threadIdx.x < s) sm[threadIdx.x] = fminf(sm[threadIdx.x], sm[threadIdx.x + s]);
        __syncthreads();
    }
    if (threadIdx.x == 0) outp[0] = sm[0];
}

// ---------------- sum(exp(-2*(d2-min))) two-stage; final stores 1/sum ----------------
__global__ void k_sumexp_part(const float* __restrict__ d2, const float* __restrict__ d2min,
                              float* __restrict__ outp, int N) {
    __shared__ float sm[256];
    float m = d2min[0];
    float s = 0.f;
    for (int i = blockIdx.x * blockDim.x + threadIdx.x; i < N; i += gridDim.x * blockDim.x)
        s += expf(-2.0f * (d2[i] - m));
    sm[threadIdx.x] = s;
    __syncthreads();
    for (int st = 128; st > 0; st >>= 1) {
        if (threadIdx.x < st) sm[threadIdx.x] += sm[threadIdx.x + st];
        __syncthreads();
    }
    if (threadIdx.x == 0) outp[blockIdx.x] = sm[0];
}

__global__ void k_sum_final_inv(const float* __restrict__ inp, float* __restrict__ outp) {
    __shared__ float sm[256];
    sm[threadIdx.x] = inp[threadIdx.x];
    __syncthreads();
    for (int st = 128; st > 0; st >>= 1) {
        if (threadIdx.x < st) sm[threadIdx.x] += sm[threadIdx.x + st];
        __syncthreads();
    }
    if (threadIdx.x == 0) outp[0] = 1.0f / sm[0];
}

// ---------------- cnorm_inv = 1 / max(||c||, eps) ----------------
__global__ void k_cnorm(const float* __restrict__ cvec, float* __restrict__ outp) {
    __shared__ float sm[512];
    float v = cvec[threadIdx.x];
    sm[threadIdx.x] = v * v;
    __syncthreads();
    for (int st = 256; st > 0; st >>= 1) {
        if (threadIdx.x < st) sm[threadIdx.x] += sm[threadIdx.x + st];
        __syncthreads();
    }
    if (threadIdx.x == 0) outp[0] = 1.0f / fmaxf(sqrtf(sm[0]), EPSF);
}

// ---------------- Wt[k][j] = W[j][k] (512x512 transpose) ----------------
__global__ void k_transpose(const float* __restrict__ W, float* __restrict__ Wt) {
    __shared__ float tile[32][33];
    int bx = blockIdx.x, by = blockIdx.y;
    int tx = threadIdx.x, ty = threadIdx.y;   // 32 x 8
    #pragma unroll
    for (int i = 0; i < 32; i += 8)
        tile[ty + i][tx] = W[(size_t)(by * 32 + ty + i) * DD + bx * 32 + tx];
    __syncthreads();
    #pragma unroll
    for (int i = 0; i < 32; i += 8)
        Wt[(size_t)(bx * 32 + ty + i) * DD + by * 32 + tx] = tile[tx][ty + i];
}

// ---------------- final: x_proj = z W^T + b; out = 1 - (x.c)/(|x||c|) ----------------
// 512 threads = 8 waves; TM=24 rows/block; each wave owns 3 full rows.
// LDS: z tile 48 KB + W k-chunk 16 KB = 64 KB -> 2 blocks/CU.
__global__ __launch_bounds__(512) void k_final(
    const float* __restrict__ z, const float* __restrict__ Wt,
    const float* __restrict__ bvec, const float* __restrict__ cvec,
    const float* __restrict__ cninv, float* __restrict__ out, int N)
{
    __shared__ float zs[TM * DD];   // 49152 B
    __shared__ float wt[KC * DD];   // 16384 B
    int t = threadIdx.x;
    int row0 = blockIdx.x * TM;

    // stage z rows (coalesced float4; rows >= N zero-filled)
    #pragma unroll
    for (int it = 0; it < 6; ++it) {
        int f = t + 512 * it;       // 0..3071
        int i = f >> 7;             // 0..23
        int kq = f & 127;           // float4 index along k
        int r = row0 + i;
        float4 v = make_float4(0.f, 0.f, 0.f, 0.f);
        if (r < N) v = ((const float4*)z)[(size_t)r * (DD / 4) + kq];
        ((float4*)(zs + i * DD))[kq] = v;
    }

    int lane = t & 63;
    int wv = t >> 6;                // 0..7
    int jbase = lane * 8;           // this lane's 8 output columns
    const int rbase = wv * 3;       // this wave's 3 rows

    float acc[3][8];
    #pragma unroll
    for (int a = 0; a < 3; ++a)
        #pragma unroll
        for (int b = 0; b < 8; ++b) acc[a][b] = 0.f;

    for (int kc = 0; kc < DD; kc += KC) {
        __syncthreads();            // protect previous wt chunk (also covers zs on iter 0)
        {   // stage k-chunk of Wt: KC*DD floats = 1024 float4, 2 per thread, coalesced
            const float4* src = (const float4*)(Wt + (size_t)kc * DD);
            float4* dst = (float4*)wt;
            dst[t]       = src[t];
            dst[t + 512] = src[t + 512];
        }
        __syncthreads();
        #pragma unroll
        for (int kk = 0; kk < KC; ++kk) {
            const float* wrow = wt + kk * DD + jbase;
            float4 w0 = ((const float4*)wrow)[0];
            float4 w1 = ((const float4*)wrow)[1];
            float zv[3];
            #pragma unroll
            for (int rr = 0; rr < 3; ++rr) zv[rr] = zs[(rbase + rr) * DD + kc + kk]; // LDS broadcast
            #pragma unroll
            for (int rr = 0; rr < 3; ++rr) {
                acc[rr][0] += zv[rr] * w0.x;
                acc[rr][1] += zv[rr] * w0.y;
                acc[rr][2] += zv[rr] * w0.z;
                acc[rr][3] += zv[rr] * w0.w;
                acc[rr][4] += zv[rr] * w1.x;
                acc[rr][5] += zv[rr] * w1.y;
                acc[rr][6] += zv[rr] * w1.z;
                acc[rr][7] += zv[rr] * w1.w;
            }
        }
    }

    // epilogue: add bias, per-row norm & dot with c via wave reduce
    float4 b0 = ((const float4*)(bvec + jbase))[0];
    float4 b1 = ((const float4*)(bvec + jbase))[1];
    float4 c0 = ((const float4*)(cvec + jbase))[0];
    float4 c1 = ((const float4*)(cvec + jbase))[1];
    float ci = cninv[0];
    #pragma unroll
    for (int rr = 0; rr < 3; ++rr) {
        int r = row0 + rbase + rr;
        float x0 = acc[rr][0] + b0.x, x1 = acc[rr][1] + b0.y;
        float x2 = acc[rr][2] + b0.z, x3 = acc[rr][3] + b0.w;
        float x4 = acc[rr][4] + b1.x, x5 = acc[rr][5] + b1.y;
        float x6 = acc[rr][6] + b1.z, x7 = acc[rr][7] + b1.w;
        float sq = x0*x0 + x1*x1 + x2*x2 + x3*x3 + x4*x4 + x5*x5 + x6*x6 + x7*x7;
        float dc = x0*c0.x + x1*c0.y + x2*c0.z + x3*c0.w
                 + x4*c1.x + x5*c1.y + x6*c1.z + x7*c1.w;
        #pragma unroll
        for (int off = 32; off > 0; off >>= 1) {
            sq += __shfl_down(sq, off, 64);
            dc += __shfl_down(dc, off, 64);
        }
        if (lane == 0 && r < N) {
            float xi = 1.0f / fmaxf(sqrtf(sq), EPSF);
            out[r] = 1.0f - dc * xi * ci;
        }
    }
}

extern "C" void kernel_launch(void* const* d_in, const int* in_sizes, int n_in,
                              void* d_out, int out_size, void* d_ws, size_t ws_size,
                              hipStream_t stream)
{
    const float* z = (const float*)d_in[0];
    const float* W = (const float*)d_in[1];
    const float* b = (const float*)d_in[2];
    float* out = (float*)d_out;
    int N = in_sizes[0] / DD;

    float* ws = (float*)d_ws;
    size_t off = 0;
    float* part  = ws + off; off += 256 * DD;     // partial col sums (reused for c partials)
    float* cbar  = ws + off; off += DD;           // init_c
    float* d2    = ws + off; off += (size_t)N;    // d2[N]
    float* minp  = ws + off; off += 256;
    float* d2min = ws + off; off += 1;
    float* sump  = ws + off; off += 256;
    float* sinv  = ws + off; off += 1;            // 1/sumexp
    float* cvec  = ws + off; off += DD;           // c
    float* cninv = ws + off; off += 1;            // 1/max(||c||,eps)
    off = (off + 3) & ~(size_t)3;                 // 16B-align Wt
    float* Wt    = ws + off; off += (size_t)DD * DD;

    k_transpose<<<dim3(16, 16), dim3(32, 8), 0, stream>>>(W, Wt);
    k_colsum<<<256, 256, 0, stream>>>(z, part, N);
    k_reduce_cols<<<2, 256, 0, stream>>>(part, cbar, 1.0f / (float)N);
    k_d2<<<256, 256, 0, stream>>>(z, cbar, d2, N);
    k_min_part<<<256, 256, 0, stream>>>(d2, minp, N);
    k_min_final<<<1, 256, 0, stream>>>(minp, d2min);
    k_sumexp_part<<<256, 256, 0, stream>>>(d2, d2min, sump, N);
    k_sum_final_inv<<<1, 256, 0, stream>>>(sump, sinv);
    k_wcolsum<<<256, 256, 0, stream>>>(z, d2, d2min, sinv, part, N);
    k_reduce_cols<<<2, 256, 0, stream>>>(part, cvec, 1.0f);
    k_cnorm<<<1, DD, 0, stream>>>(cvec, cninv);
    int nblk = (N + TM - 1) / TM;
    k_final<<<nblk, 512, 0, stream>>>(z, Wt, b, cvec, cninv, out, N);
}

// Round 2
// 1004.025 us; speedup vs baseline: 2.8869x; 2.8869x over previous
//
#include <hip/hip_runtime.h>
#include <hip/hip_bf16.h>
#include <math.h>

#define DD 512
#define EPSF 1e-8f
#define BM 64
#define BK 32

typedef __bf16 bf16_t;
typedef __bf16 bf16x4 __attribute__((ext_vector_type(4)));
typedef __bf16 bf16x8 __attribute__((ext_vector_type(8)));
typedef float f32x4 __attribute__((ext_vector_type(4)));

// ---------------- W fp32 -> bf16 (native [j][k] layout) ----------------
__global__ void k_convW(const float* __restrict__ W, bf16_t* __restrict__ Wb) {
    int i = blockIdx.x * blockDim.x + threadIdx.x;   // 65536 threads x 4 elems
    float4 v = ((const float4*)W)[i];
    bf16x4 o;
    o[0] = (bf16_t)v.x; o[1] = (bf16_t)v.y; o[2] = (bf16_t)v.z; o[3] = (bf16_t)v.w;
    ((bf16x4*)Wb)[i] = o;
}

// ---------------- partial column sums (for init_c) ----------------
__global__ void k_colsum(const float* __restrict__ z, float* __restrict__ part, int N) {
    int t = threadIdx.x;          // 0..255 -> float2 column index
    int b = blockIdx.x;           // 0..1023
    const float2* z2 = (const float2*)z;
    float2 acc = make_float2(0.f, 0.f);
    #pragma unroll 4
    for (int r = b; r < N; r += gridDim.x) {
        float2 v = z2[(size_t)r * (DD / 2) + t];
        acc.x += v.x; acc.y += v.y;
    }
    part[(size_t)b * DD + 2 * t]     = acc.x;
    part[(size_t)b * DD + 2 * t + 1] = acc.y;
}

// ---------------- weighted partial column sums (for c) ----------------
__global__ void k_wcolsum(const float* __restrict__ z, const float* __restrict__ d2,
                          const float* __restrict__ d2min, const float* __restrict__ sinv,
                          float* __restrict__ part, int N) {
    int t = threadIdx.x;
    int b = blockIdx.x;
    float m  = d2min[0];
    float is = sinv[0];
    const float2* z2 = (const float2*)z;
    float2 acc = make_float2(0.f, 0.f);
    #pragma unroll 2
    for (int r = b; r < N; r += gridDim.x) {
        float w = expf(-2.0f * (d2[r] - m)) * is;   // softmax(-d2/tau), tau=0.5
        float2 v = z2[(size_t)r * (DD / 2) + t];
        acc.x += w * v.x; acc.y += w * v.y;
    }
    part[(size_t)b * DD + 2 * t]     = acc.x;
    part[(size_t)b * DD + 2 * t + 1] = acc.y;
}

// reduce 1024 partial vectors -> one [512] vector; one block per column
__global__ void k_reduce1024(const float* __restrict__ part, float* __restrict__ outv, float scale) {
    __shared__ float sm[256];
    int j = blockIdx.x;           // column 0..511
    int t = threadIdx.x;
    float s = part[(size_t)t * DD + j] + part[(size_t)(t + 256) * DD + j]
            + part[(size_t)(t + 512) * DD + j] + part[(size_t)(t + 768) * DD + j];
    sm[t] = s;
    __syncthreads();
    for (int st = 128; st > 0; st >>= 1) {
        if (t < st) sm[t] += sm[t + st];
        __syncthreads();
    }
    if (t == 0) outv[j] = sm[0] * scale;
}

// ---------------- d2[i] = ||z_i - init_c||^2, one wave per row ----------------
__global__ void k_d2(const float* __restrict__ z, const float* __restrict__ cbar,
                     float* __restrict__ d2, int N) {
    int lane = threadIdx.x & 63;
    int gw = (blockIdx.x * blockDim.x + threadIdx.x) >> 6;
    int nw = (gridDim.x * blockDim.x) >> 6;
    const float4* c4 = (const float4*)cbar;
    float4 ca = c4[lane];
    float4 cb = c4[lane + 64];
    for (int r = gw; r < N; r += nw) {
        const float4* zr = (const float4*)(z + (size_t)r * DD);
        float4 a  = zr[lane];
        float4 bb = zr[lane + 64];
        float d, s = 0.f;
        d = a.x  - ca.x; s += d * d;
        d = a.y  - ca.y; s += d * d;
        d = a.z  - ca.z; s += d * d;
        d = a.w  - ca.w; s += d * d;
        d = bb.x - cb.x; s += d * d;
        d = bb.y - cb.y; s += d * d;
        d = bb.z - cb.z; s += d * d;
        d = bb.w - cb.w; s += d * d;
        #pragma unroll
        for (int off = 32; off > 0; off >>= 1) s += __shfl_down(s, off, 64);
        if (lane == 0) d2[r] = s;
    }
}

// ---------------- min(d2) two-stage ----------------
__global__ void k_min_part(const float* __restrict__ d2, float* __restrict__ outp, int N) {
    __shared__ float sm[256];
    float m = 3.402823466e+38f;
    for (int i = blockIdx.x * blockDim.x + threadIdx.x; i < N; i += gridDim.x * blockDim.x)
        m = fminf(m, d2[i]);
    sm[threadIdx.x] = m;
    __syncthreads();
    for (int s = 128; s > 0; s >>= 1) {
        if (threadIdx.x < s) sm[threadIdx.x] = fminf(sm[threadIdx.x], sm[threadIdx.x + s]);
        __syncthreads();
    }
    if (threadIdx.x == 0) outp[blockIdx.x] = sm[0];
}

__global__ void k_min_final(const float* __restrict__ inp, float* __restrict__ outp) {
    __shared__ float sm[256];
    sm[threadIdx.x] = inp[threadIdx.x];
    __syncthreads();
    for (int s = 128; s > 0; s >>= 1) {
        if (threadIdx.x < s) sm[threadIdx.x] = fminf(sm[threadIdx.x], sm[threadIdx.x + s]);
        __syncthreads();
    }
    if (threadIdx.x == 0) outp[0] = sm[0];
}

// ---------------- sum(exp(-2*(d2-min))) two-stage; final stores 1/sum ----------------
__global__ void k_sumexp_part(const float* __restrict__ d2, const float* __restrict__ d2min,
                              float* __restrict__ outp, int N) {
    __shared__ float sm[256];
    float m = d2min[0];
    float s = 0.f;
    for (int i = blockIdx.x * blockDim.x + threadIdx.x; i < N; i += gridDim.x * blockDim.x)
        s += expf(-2.0f * (d2[i] - m));
    sm[threadIdx.x] = s;
    __syncthreads();
    for (int st = 128; st > 0; st >>= 1) {
        if (threadIdx.x < st) sm[threadIdx.x] += sm[threadIdx.x + st];
        __syncthreads();
    }
    if (threadIdx.x == 0) outp[blockIdx.x] = sm[0];
}

__global__ void k_sum_final_inv(const float* __restrict__ inp, float* __restrict__ outp) {
    __shared__ float sm[256];
    sm[threadIdx.x] = inp[threadIdx.x];
    __syncthreads();
    for (int st = 128; st > 0; st >>= 1) {
        if (threadIdx.x < st) sm[threadIdx.x] += sm[threadIdx.x + st];
        __syncthreads();
    }
    if (threadIdx.x == 0) outp[0] = 1.0f / sm[0];
}

// ---------------- cnorm_inv = 1 / max(||c||, eps) ----------------
__global__ void k_cnorm(const float* __restrict__ cvec, float* __restrict__ outp) {
    __shared__ float sm[512];
    float v = cvec[threadIdx.x];
    sm[threadIdx.x] = v * v;
    __syncthreads();
    for (int st = 256; st > 0; st >>= 1) {
        if (threadIdx.x < st) sm[threadIdx.x] += sm[threadIdx.x + st];
        __syncthreads();
    }
    if (threadIdx.x == 0) outp[0] = 1.0f / fmaxf(sqrtf(sm[0]), EPSF);
}

// ---------------- fused MFMA GEMM + cosine-dist epilogue ----------------
// 512 threads = 8 waves. M-tile = 64 rows, all 512 cols, K-chunks of 32.
// Wave (wr,wc): row-tiles {2wr, 2wr+1}, col-tiles [8wc .. 8wc+7].
// A = z (fp32 -> bf16 inline). B = W bf16, NATIVE [j][k] layout (= B-operand
// [n][k-contiguous]), staged via global_load_lds width 16.
__global__ __launch_bounds__(512) void k_gemm(
    const float* __restrict__ z, const bf16_t* __restrict__ Wb,
    const float* __restrict__ bvec, const float* __restrict__ cvec,
    const float* __restrict__ cninv, float* __restrict__ out, int N)
{
    __shared__ bf16_t As[BM * BK];      // 4 KB   [m][k]
    __shared__ bf16_t Bs[DD * BK];      // 32 KB  [n][k]
    __shared__ float psq[BM][4];
    __shared__ float pdt[BM][4];

    const int t    = threadIdx.x;
    const int lane = t & 63;
    const int wv   = t >> 6;            // 0..7
    const int wr   = wv >> 2;           // 0..1
    const int wc   = wv & 3;            // 0..3
    const int quad = lane >> 4;         // 0..3
    const int l15  = lane & 15;
    const int row0 = blockIdx.x * BM;

    // A staging: thread t -> row ai, float4 slot aq (k = 4*aq within chunk)
    const int ai = t >> 3;              // 0..63
    const int aq = t & 7;               // 0..7
    const float4* zsrc = (const float4*)(z + (size_t)(row0 + ai) * DD) + aq;
    const bool arow_ok = (row0 + ai) < N;

    // B staging: round q stages rows j = q*128 + (t>>2), 16 B at k-offset (t&3)*8
    const int bj = t >> 2;              // 0..127
    const int bk = (t & 3) * 8;

    f32x4 acc[2][8];
    #pragma unroll
    for (int a = 0; a < 2; ++a)
        #pragma unroll
        for (int b = 0; b < 8; ++b) acc[a][b] = (f32x4){0.f, 0.f, 0.f, 0.f};

    for (int kc = 0; kc < DD; kc += BK) {
        // --- stage B: 4 rounds of 512 lanes x 16 B = 32 KB, async into LDS
        #pragma unroll
        for (int q = 0; q < 4; ++q) {
            const bf16_t* gp = Wb + (size_t)(q * 128 + bj) * DD + kc + bk;
            int ldsoff = __builtin_amdgcn_readfirstlane(q * 8192 + wv * 1024);
            __builtin_amdgcn_global_load_lds(
                (const __attribute__((address_space(1))) unsigned int*)(const void*)gp,
                (__attribute__((address_space(3))) unsigned int*)(void*)((char*)Bs + ldsoff),
                16, 0, 0);
        }
        // --- stage A: fp32 load -> bf16 -> LDS (8 B per thread)
        float4 v = make_float4(0.f, 0.f, 0.f, 0.f);
        if (arow_ok) v = zsrc[kc >> 2];
        bf16x4 a4;
        a4[0] = (bf16_t)v.x; a4[1] = (bf16_t)v.y; a4[2] = (bf16_t)v.z; a4[3] = (bf16_t)v.w;
        *(bf16x4*)(As + ai * BK + 4 * aq) = a4;

        asm volatile("s_waitcnt vmcnt(0) lgkmcnt(0)" ::: "memory");
        __syncthreads();

        // --- compute: 2 A-frags, 8 B-frags, 16 MFMA
        bf16x8 af0 = *(const bf16x8*)(As + (wr * 32 + l15) * BK + quad * 8);
        bf16x8 af1 = *(const bf16x8*)(As + (wr * 32 + 16 + l15) * BK + quad * 8);
        #pragma unroll
        for (int ct = 0; ct < 8; ++ct) {
            bf16x8 bf = *(const bf16x8*)(Bs + (wc * 128 + ct * 16 + l15) * BK + quad * 8);
            acc[0][ct] = __builtin_amdgcn_mfma_f32_16x16x32_bf16(af0, bf, acc[0][ct], 0, 0, 0);
            acc[1][ct] = __builtin_amdgcn_mfma_f32_16x16x32_bf16(af1, bf, acc[1][ct], 0, 0, 0);
        }
        __syncthreads();
    }

    // --- epilogue: x = acc + b[col]; reduce sq and dot(c) per row
    float bc[8], cc[8];
    #pragma unroll
    for (int ct = 0; ct < 8; ++ct) {
        int col = wc * 128 + ct * 16 + l15;
        bc[ct] = bvec[col];
        cc[ct] = cvec[col];
    }
    #pragma unroll
    for (int rt = 0; rt < 2; ++rt) {
        #pragma unroll
        for (int rg = 0; rg < 4; ++rg) {
            float sq = 0.f, dt = 0.f;
            #pragma unroll
            for (int ct = 0; ct < 8; ++ct) {
                float x = acc[rt][ct][rg] + bc[ct];
                sq += x * x;
                dt += x * cc[ct];
            }
            #pragma unroll
            for (int off = 1; off < 16; off <<= 1) {
                sq += __shfl_xor(sq, off, 64);
                dt += __shfl_xor(dt, off, 64);
            }
            if (l15 == 0) {
                int rl = wr * 32 + rt * 16 + quad * 4 + rg;
                psq[rl][wc] = sq;
                pdt[rl][wc] = dt;
            }
        }
    }
    __syncthreads();
    if (t < BM) {
        int r = row0 + t;
        if (r < N) {
            float sq = psq[t][0] + psq[t][1] + psq[t][2] + psq[t][3];
            float dt = pdt[t][0] + pdt[t][1] + pdt[t][2] + pdt[t][3];
            float xi = 1.0f / fmaxf(sqrtf(sq), EPSF);
            out[r] = 1.0f - dt * xi * cninv[0];
        }
    }
}

extern "C" void kernel_launch(void* const* d_in, const int* in_sizes, int n_in,
                              void* d_out, int out_size, void* d_ws, size_t ws_size,
                              hipStream_t stream)
{
    const float* z = (const float*)d_in[0];
    const float* W = (const float*)d_in[1];
    const float* b = (const float*)d_in[2];
    float* out = (float*)d_out;
    int N = in_sizes[0] / DD;

    float* ws = (float*)d_ws;
    size_t off = 0;
    float* part  = ws + off; off += (size_t)1024 * DD;  // partial col sums
    float* cbar  = ws + off; off += DD;                 // init_c
    float* d2    = ws + off; off += (size_t)N;          // d2[N]
    float* minp  = ws + off; off += 256;
    float* d2min = ws + off; off += 1;
    float* sump  = ws + off; off += 256;
    float* sinv  = ws + off; off += 1;                  // 1/sumexp
    float* cvec  = ws + off; off += DD;                 // c
    float* cninv = ws + off; off += 1;                  // 1/max(||c||,eps)
    off = (off + 3) & ~(size_t)3;                       // 16B-align
    bf16_t* Wb   = (bf16_t*)(ws + off);                 // W in bf16, native layout

    k_convW<<<256, 256, 0, stream>>>(W, Wb);
    k_colsum<<<1024, 256, 0, stream>>>(z, part, N);
    k_reduce1024<<<DD, 256, 0, stream>>>(part, cbar, 1.0f / (float)N);
    k_d2<<<1024, 256, 0, stream>>>(z, cbar, d2, N);
    k_min_part<<<256, 256, 0, stream>>>(d2, minp, N);
    k_min_final<<<1, 256, 0, stream>>>(minp, d2min);
    k_sumexp_part<<<256, 256, 0, stream>>>(d2, d2min, sump, N);
    k_sum_final_inv<<<1, 256, 0, stream>>>(sump, sinv);
    k_wcolsum<<<1024, 256, 0, stream>>>(z, d2, d2min, sinv, part, N);
    k_reduce1024<<<DD, 256, 0, stream>>>(part, cvec, 1.0f);
    k_cnorm<<<1, DD, 0, stream>>>(cvec, cninv);
    int nblk = (N + BM - 1) / BM;
    k_gemm<<<nblk, 512, 0, stream>>>(z, Wb, b, cvec, cninv, out, N);
}

// Round 3
// 931.363 us; speedup vs baseline: 3.1122x; 1.0780x over previous
//
#include <hip/hip_runtime.h>
#include <hip/hip_bf16.h>
#include <math.h>

#define DD 512
#define EPSF 1e-8f
#define BM 128
#define BK 32
#define FBIG 3.402823466e+38f

typedef __bf16 bf16_t;
typedef __bf16 bf16x4 __attribute__((ext_vector_type(4)));
typedef __bf16 bf16x8 __attribute__((ext_vector_type(8)));
typedef float f32x4 __attribute__((ext_vector_type(4)));

// ---------------- W fp32 -> bf16 (native [j][k] layout) ----------------
__global__ void k_convW(const float* __restrict__ W, bf16_t* __restrict__ Wb) {
    int i = blockIdx.x * blockDim.x + threadIdx.x;   // 65536 threads x 4 elems
    float4 v = ((const float4*)W)[i];
    bf16x4 o;
    o[0] = (bf16_t)v.x; o[1] = (bf16_t)v.y; o[2] = (bf16_t)v.z; o[3] = (bf16_t)v.w;
    ((bf16x4*)Wb)[i] = o;
}

// ---------------- partial column sums (for init_c), float4 ----------------
__global__ void k_colsum(const float* __restrict__ z, float* __restrict__ part, int N) {
    int t = threadIdx.x;                 // 256
    int b = blockIdx.x;                  // 1024
    int col4 = t & 127, sub = t >> 7;    // 2 rows per iteration
    const float4* z4 = (const float4*)z;
    float4 acc = make_float4(0.f, 0.f, 0.f, 0.f);
    int npair = (N + 1) >> 1;
    #pragma unroll 2
    for (int p = b; p < npair; p += gridDim.x) {
        int r = p * 2 + sub;
        if (r < N) {
            float4 v = z4[(size_t)r * 128 + col4];
            acc.x += v.x; acc.y += v.y; acc.z += v.z; acc.w += v.w;
        }
    }
    __shared__ float4 sm[128];
    if (sub == 1) sm[col4] = acc;
    __syncthreads();
    if (sub == 0) {
        float4 o = sm[col4];
        acc.x += o.x; acc.y += o.y; acc.z += o.z; acc.w += o.w;
        ((float4*)(part + (size_t)b * DD))[col4] = acc;
    }
}

// ---------------- weighted partial column sums (for c), float4 ----------------
__global__ void k_wcolsum(const float* __restrict__ z, const float* __restrict__ d2,
                          const float* __restrict__ d2min, const float* __restrict__ sinvp,
                          float* __restrict__ part, int N) {
    int t = threadIdx.x;
    int b = blockIdx.x;
    int col4 = t & 127, sub = t >> 7;
    float m  = d2min[0];
    float is = sinvp[0];
    const float4* z4 = (const float4*)z;
    float4 acc = make_float4(0.f, 0.f, 0.f, 0.f);
    int npair = (N + 1) >> 1;
    #pragma unroll 2
    for (int p = b; p < npair; p += gridDim.x) {
        int r = p * 2 + sub;
        if (r < N) {
            float w = __expf(-2.0f * (d2[r] - m)) * is;   // softmax(-d2/tau), tau=0.5
            float4 v = z4[(size_t)r * 128 + col4];
            acc.x += w * v.x; acc.y += w * v.y; acc.z += w * v.z; acc.w += w * v.w;
        }
    }
    __shared__ float4 sm[128];
    if (sub == 1) sm[col4] = acc;
    __syncthreads();
    if (sub == 0) {
        float4 o = sm[col4];
        acc.x += o.x; acc.y += o.y; acc.z += o.z; acc.w += o.w;
        ((float4*)(part + (size_t)b * DD))[col4] = acc;
    }
}

// reduce 1024 partial vectors -> one [512] vector; one block per column
__global__ void k_reduce1024(const float* __restrict__ part, float* __restrict__ outv, float scale) {
    __shared__ float sm[256];
    int j = blockIdx.x;
    int t = threadIdx.x;
    float s = part[(size_t)t * DD + j] + part[(size_t)(t + 256) * DD + j]
            + part[(size_t)(t + 512) * DD + j] + part[(size_t)(t + 768) * DD + j];
    sm[t] = s;
    __syncthreads();
    for (int st = 128; st > 0; st >>= 1) {
        if (t < st) sm[t] += sm[t + st];
        __syncthreads();
    }
    if (t == 0) outv[j] = sm[0] * scale;
}

// ---------------- d2 + fused online softmax partials ----------------
// one wave per row; every lane keeps (m,s) online-softmax state; block writes
// combined (m_b, s_b) so the global min/sumexp passes disappear.
__global__ void k_d2s(const float* __restrict__ z, const float* __restrict__ cbar,
                      float* __restrict__ d2, float* __restrict__ mpart,
                      float* __restrict__ spart, int N) {
    int lane = threadIdx.x & 63;
    int wvid = threadIdx.x >> 6;                       // 0..3
    int gw = (blockIdx.x * blockDim.x + threadIdx.x) >> 6;
    int nw = (gridDim.x * blockDim.x) >> 6;
    const float4* c4 = (const float4*)cbar;
    float4 ca = c4[lane];
    float4 cb = c4[lane + 64];
    float m = FBIG, s = 0.f;
    for (int r = gw; r < N; r += nw) {
        const float4* zr = (const float4*)(z + (size_t)r * DD);
        float4 a  = zr[lane];
        float4 bb = zr[lane + 64];
        float d, sum = 0.f;
        d = a.x  - ca.x; sum += d * d;
        d = a.y  - ca.y; sum += d * d;
        d = a.z  - ca.z; sum += d * d;
        d = a.w  - ca.w; sum += d * d;
        d = bb.x - cb.x; sum += d * d;
        d = bb.y - cb.y; sum += d * d;
        d = bb.z - cb.z; sum += d * d;
        d = bb.w - cb.w; sum += d * d;
        #pragma unroll
        for (int off = 1; off < 64; off <<= 1) sum += __shfl_xor(sum, off, 64);
        if (lane == 0) d2[r] = sum;
        float nm = fminf(m, sum);
        s = s * __expf(-2.0f * (m - nm)) + __expf(-2.0f * (sum - nm));
        m = nm;
    }
    __shared__ float smm[4], sms[4];
    if (lane == 0) { smm[wvid] = m; sms[wvid] = s; }
    __syncthreads();
    if (threadIdx.x == 0) {
        float M = smm[0];
        M = fminf(M, smm[1]); M = fminf(M, smm[2]); M = fminf(M, smm[3]);
        float S = 0.f;
        #pragma unroll
        for (int i = 0; i < 4; ++i) S += sms[i] * __expf(-2.0f * (smm[i] - M));
        mpart[blockIdx.x] = M;
        spart[blockIdx.x] = S;
    }
}

// combine 1024 (m,s) partials -> d2min, 1/sumexp
__global__ void k_combine(const float* __restrict__ mpart, const float* __restrict__ spart,
                          float* __restrict__ d2min, float* __restrict__ sinvp) {
    __shared__ float smm[256], sms[256];
    int t = threadIdx.x;
    float M = FBIG, S = 0.f;
    for (int i = t; i < 1024; i += 256) {
        float m2 = mpart[i], s2 = spart[i];
        float nm = fminf(M, m2);
        S = S * __expf(-2.0f * (M - nm)) + s2 * __expf(-2.0f * (m2 - nm));
        M = nm;
    }
    smm[t] = M; sms[t] = S;
    __syncthreads();
    for (int st = 128; st > 0; st >>= 1) {
        if (t < st) {
            float m2 = smm[t + st], s2 = sms[t + st];
            float nm = fminf(smm[t], m2);
            sms[t] = sms[t] * __expf(-2.0f * (smm[t] - nm)) + s2 * __expf(-2.0f * (m2 - nm));
            smm[t] = nm;
        }
        __syncthreads();
    }
    if (t == 0) { d2min[0] = smm[0]; sinvp[0] = 1.0f / sms[0]; }
}

// ---------------- cnorm_inv = 1 / max(||c||, eps) ----------------
__global__ void k_cnorm(const float* __restrict__ cvec, float* __restrict__ outp) {
    __shared__ float sm[512];
    float v = cvec[threadIdx.x];
    sm[threadIdx.x] = v * v;
    __syncthreads();
    for (int st = 256; st > 0; st >>= 1) {
        if (threadIdx.x < st) sm[threadIdx.x] += sm[threadIdx.x + st];
        __syncthreads();
    }
    if (threadIdx.x == 0) outp[0] = 1.0f / fmaxf(sqrtf(sm[0]), EPSF);
}

// ---------------- fused MFMA GEMM + cosine-dist epilogue ----------------
// BM=128 x all 512 cols, BK=32, 512 thr = 8 waves (2x4 grid, 4x8 tiles/wave).
// Double-buffered LDS, ONE barrier per chunk: B-DMA + A-reg loads for chunk
// k+1 issue before computing chunk k, so vmcnt(0) drains after ~full compute.
__global__ __launch_bounds__(512, 2) void k_gemm(
    const float* __restrict__ z, const bf16_t* __restrict__ Wb,
    const float* __restrict__ bvec, const float* __restrict__ cvec,
    const float* __restrict__ cninv, float* __restrict__ out, int N)
{
    __shared__ bf16_t As[2][BM * BK];   // 2 x 8 KB   [m][k]
    __shared__ bf16_t Bs[2][DD * BK];   // 2 x 32 KB  [n][k]
    __shared__ float psq[BM][4];
    __shared__ float pdt[BM][4];

    const int t    = threadIdx.x;
    const int lane = t & 63;
    const int wv   = t >> 6;            // 0..7
    const int wr   = wv >> 2;           // 0..1  (row half)
    const int wc   = wv & 3;            // 0..3  (col quarter)
    const int quad = lane >> 4;         // 0..3
    const int l15  = lane & 15;
    const int row0 = blockIdx.x * BM;

    // A staging: thread t -> row ai (0..127), k-offset ak (0,8,16,24), 8 floats
    const int ai = t >> 2;
    const int ak = (t & 3) * 8;
    const bool arow_ok = (row0 + ai) < N;
    const float4* zrow = (const float4*)(z + (size_t)(row0 + ai) * DD + ak);

    // B staging: per DMA round q, lane t -> row (t>>2), 16 B at k-off (t&3)*8
    const bf16_t* bsrc = Wb + (size_t)(t >> 2) * DD + (t & 3) * 8;

    f32x4 acc[4][8];
    #pragma unroll
    for (int a = 0; a < 4; ++a)
        #pragma unroll
        for (int b = 0; b < 8; ++b) acc[a][b] = (f32x4){0.f, 0.f, 0.f, 0.f};

    // ---- prologue: stage chunk 0 into buffer 0
    #pragma unroll
    for (int q = 0; q < 4; ++q) {
        int ldsoff = __builtin_amdgcn_readfirstlane(q * 8192 + wv * 1024);
        __builtin_amdgcn_global_load_lds(
            (const __attribute__((address_space(1))) unsigned int*)(const void*)(bsrc + (size_t)q * 128 * DD),
            (__attribute__((address_space(3))) unsigned int*)(void*)((char*)&Bs[0][0] + ldsoff),
            16, 0, 0);
    }
    {
        float4 v0 = make_float4(0.f,0.f,0.f,0.f), v1 = v0;
        if (arow_ok) { v0 = zrow[0]; v1 = zrow[1]; }
        bf16x8 a8;
        a8[0]=(bf16_t)v0.x; a8[1]=(bf16_t)v0.y; a8[2]=(bf16_t)v0.z; a8[3]=(bf16_t)v0.w;
        a8[4]=(bf16_t)v1.x; a8[5]=(bf16_t)v1.y; a8[6]=(bf16_t)v1.z; a8[7]=(bf16_t)v1.w;
        *(bf16x8*)(&As[0][ai * BK + ak]) = a8;
    }
    asm volatile("s_waitcnt vmcnt(0)" ::: "memory");
    __syncthreads();

    #pragma unroll 1
    for (int kc2 = 0; kc2 < 16; ++kc2) {
        const int cur = kc2 & 1;
        const int nxt = cur ^ 1;
        float4 v0 = make_float4(0.f,0.f,0.f,0.f), v1 = v0;
        if (kc2 < 15) {
            const int kc = (kc2 + 1) * BK;
            #pragma unroll
            for (int q = 0; q < 4; ++q) {
                int ldsoff = __builtin_amdgcn_readfirstlane(q * 8192 + wv * 1024);
                __builtin_amdgcn_global_load_lds(
                    (const __attribute__((address_space(1))) unsigned int*)(const void*)(bsrc + (size_t)q * 128 * DD + kc),
                    (__attribute__((address_space(3))) unsigned int*)(void*)((char*)&Bs[nxt][0] + ldsoff),
                    16, 0, 0);
            }
            if (arow_ok) { v0 = zrow[kc >> 2]; v1 = zrow[(kc >> 2) + 1]; }
        }

        // ---- compute chunk kc2 from buffer cur: 4 A-frags, 8 B-frags, 32 MFMA
        bf16x8 af[4];
        #pragma unroll
        for (int rt = 0; rt < 4; ++rt)
            af[rt] = *(const bf16x8*)(&As[cur][(wr * 64 + rt * 16 + l15) * BK + quad * 8]);
        #pragma unroll
        for (int ct = 0; ct < 8; ++ct) {
            bf16x8 bfv = *(const bf16x8*)(&Bs[cur][(wc * 128 + ct * 16 + l15) * BK + quad * 8]);
            #pragma unroll
            for (int rt = 0; rt < 4; ++rt)
                acc[rt][ct] = __builtin_amdgcn_mfma_f32_16x16x32_bf16(af[rt], bfv, acc[rt][ct], 0, 0, 0);
        }

        if (kc2 < 15) {
            bf16x8 a8;
            a8[0]=(bf16_t)v0.x; a8[1]=(bf16_t)v0.y; a8[2]=(bf16_t)v0.z; a8[3]=(bf16_t)v0.w;
            a8[4]=(bf16_t)v1.x; a8[5]=(bf16_t)v1.y; a8[6]=(bf16_t)v1.z; a8[7]=(bf16_t)v1.w;
            *(bf16x8*)(&As[nxt][ai * BK + ak]) = a8;
        }
        asm volatile("s_waitcnt vmcnt(0)" ::: "memory");
        __syncthreads();
    }

    // ---- epilogue: x = acc + b[col]; per-row sq and dot(c)
    float bc[8], cc[8];
    #pragma unroll
    for (int ct = 0; ct < 8; ++ct) {
        int col = wc * 128 + ct * 16 + l15;
        bc[ct] = bvec[col];
        cc[ct] = cvec[col];
    }
    #pragma unroll
    for (int rt = 0; rt < 4; ++rt) {
        #pragma unroll
        for (int rg = 0; rg < 4; ++rg) {
            float sq = 0.f, dt = 0.f;
            #pragma unroll
            for (int ct = 0; ct < 8; ++ct) {
                float x = acc[rt][ct][rg] + bc[ct];
                sq += x * x;
                dt += x * cc[ct];
            }
            #pragma unroll
            for (int off = 1; off < 16; off <<= 1) {
                sq += __shfl_xor(sq, off, 64);
                dt += __shfl_xor(dt, off, 64);
            }
            if (l15 == 0) {
                int rl = wr * 64 + rt * 16 + quad * 4 + rg;
                psq[rl][wc] = sq;
                pdt[rl][wc] = dt;
            }
        }
    }
    __syncthreads();
    if (t < BM) {
        int r = row0 + t;
        if (r < N) {
            float sq = psq[t][0] + psq[t][1] + psq[t][2] + psq[t][3];
            float dt = pdt[t][0] + pdt[t][1] + pdt[t][2] + pdt[t][3];
            float xi = 1.0f / fmaxf(sqrtf(sq), EPSF);
            out[r] = 1.0f - dt * xi * cninv[0];
        }
    }
}

extern "C" void kernel_launch(void* const* d_in, const int* in_sizes, int n_in,
                              void* d_out, int out_size, void* d_ws, size_t ws_size,
                              hipStream_t stream)
{
    const float* z = (const float*)d_in[0];
    const float* W = (const float*)d_in[1];
    const float* b = (const float*)d_in[2];
    float* out = (float*)d_out;
    int N = in_sizes[0] / DD;

    float* ws = (float*)d_ws;
    size_t off = 0;
    float* part  = ws + off; off += (size_t)1024 * DD;  // partial col sums
    float* cbar  = ws + off; off += DD;                 // init_c
    float* d2    = ws + off; off += (size_t)N;          // d2[N]
    float* mpart = ws + off; off += 1024;
    float* spart = ws + off; off += 1024;
    float* d2min = ws + off; off += 1;
    float* sinvp = ws + off; off += 1;                  // 1/sumexp
    float* cvec  = ws + off; off += DD;                 // c
    float* cninv = ws + off; off += 1;                  // 1/max(||c||,eps)
    off = (off + 3) & ~(size_t)3;                       // 16B-align
    bf16_t* Wb   = (bf16_t*)(ws + off);                 // W in bf16, native layout

    k_convW<<<256, 256, 0, stream>>>(W, Wb);
    k_colsum<<<1024, 256, 0, stream>>>(z, part, N);
    k_reduce1024<<<DD, 256, 0, stream>>>(part, cbar, 1.0f / (float)N);
    k_d2s<<<1024, 256, 0, stream>>>(z, cbar, d2, mpart, spart, N);
    k_combine<<<1, 256, 0, stream>>>(mpart, spart, d2min, sinvp);
    k_wcolsum<<<1024, 256, 0, stream>>>(z, d2, d2min, sinvp, part, N);
    k_reduce1024<<<DD, 256, 0, stream>>>(part, cvec, 1.0f);
    k_cnorm<<<1, DD, 0, stream>>>(cvec, cninv);
    int nblk = (N + BM - 1) / BM;
    k_gemm<<<nblk, 512, 0, stream>>>(z, Wb, b, cvec, cninv, out, N);
}